// Round 10
// baseline (209.294 us; speedup 1.0000x reference)
//
#include <hip/hip_runtime.h>
#include <math.h>

typedef unsigned short u16;
typedef unsigned int u32;
typedef short v8s __attribute__((ext_vector_type(8)));
typedef float v4f __attribute__((ext_vector_type(4)));
typedef u16 u16x4v __attribute__((ext_vector_type(4)));
typedef u16 u16x8v __attribute__((ext_vector_type(8)));
typedef u32 u32x2 __attribute__((ext_vector_type(2)));

#define S_LEN 2048
#define D_MODEL 1024
#define DH 64
#define BS_ROWS 4096  // B*S

// Q prescale: 1/sqrt(64) * log2(e), so softmax exp(x/8) == 2^(q_scaled . k)
#define QSCALE 0.1803368801111204f

#if __has_builtin(__builtin_amdgcn_exp2f)
#define EXP2(x) __builtin_amdgcn_exp2f(x)
#else
#define EXP2(x) __expf(0.6931471805599453f * (x))
#endif

__device__ __forceinline__ u16 f2bf(float f) {
    union { float f; unsigned int u; } c; c.f = f;
    unsigned int u = c.u;
    unsigned int r = (u + 0x7FFFu + ((u >> 16) & 1u)) >> 16;
    return (u16)r;
}
// pack two positive finite floats to bf16 pair (round-to-nearest, no tie-even)
__device__ __forceinline__ u32 pack2bf(float a, float b) {
    u32 ua = __float_as_uint(a) + 0x8000u;
    u32 ub = __float_as_uint(b) + 0x8000u;
    return (ua >> 16) | (ub & 0xFFFF0000u);
}

__device__ __forceinline__ v4f mfma16(v8s a, v8s b, v4f c) {
    return __builtin_amdgcn_mfma_f32_16x16x32_bf16(a, b, c, 0, 0, 0);
}

// async global->LDS, 16B per lane; LDS dest = base + lane*16 (wave-uniform base)
__device__ __forceinline__ void gl_lds(const u16* g, u16* l) {
    __builtin_amdgcn_global_load_lds(
        (const __attribute__((address_space(1))) void*)g,
        (__attribute__((address_space(3))) void*)l, 16, 0, 0);
}

// ---------------- prep: cast x (blocks 0..4095) + pack W^T (blocks 4096..5119) ----
__global__ __launch_bounds__(256) void prep_kernel(const float* __restrict__ x,
                                                   const float* __restrict__ Wq,
                                                   const float* __restrict__ Wk,
                                                   const float* __restrict__ Wv,
                                                   const float* __restrict__ Wo,
                                                   u16* __restrict__ xb,
                                                   u16* __restrict__ wqkv,
                                                   u16* __restrict__ wo_t) {
    __shared__ u16 tile[64][72];
    int blk = blockIdx.x;
    int t = threadIdx.x;
    if (blk < 4096) {
        int i = blk * 256 + t;
        float4 v = ((const float4*)x)[i];
        u16x4v o;
        o[0] = f2bf(v.x); o[1] = f2bf(v.y); o[2] = f2bf(v.z); o[3] = f2bf(v.w);
        ((u16x4v*)xb)[i] = o;
        return;
    }
    int pb = blk - 4096;
    int z = pb >> 8;  // 0..3
    pb &= 255;
    const float* w = (z == 0) ? Wq : (z == 1) ? Wk : (z == 2) ? Wv : Wo;
    u16* wt = (z < 3) ? (wqkv + (size_t)z * 1024 * 1024) : wo_t;
    int k0 = (pb & 15) * 64, n0 = (pb >> 4) * 64;
    int tr = t >> 4;          // 0..15
    int tc = (t & 15) * 4;    // 0..60
#pragma unroll
    for (int i = 0; i < 4; ++i) {
        int k = tr + 16 * i;
        float4 v = *(const float4*)(w + (size_t)(k0 + k) * 1024 + n0 + tc);
        tile[tc + 0][k] = f2bf(v.x);
        tile[tc + 1][k] = f2bf(v.y);
        tile[tc + 2][k] = f2bf(v.z);
        tile[tc + 3][k] = f2bf(v.w);
    }
    __syncthreads();
#pragma unroll
    for (int i = 0; i < 4; ++i) {
        int n = tr + 16 * i;
        u16x4v o;
        o[0] = tile[n][tc]; o[1] = tile[n][tc + 1];
        o[2] = tile[n][tc + 2]; o[3] = tile[n][tc + 3];
        *(u16x4v*)(wt + (size_t)(n0 + n) * 1024 + k0 + tc) = o;
    }
}

// ---------------- GEMM: C[M,N] = A[M,K] x Bt[N,K] ----------------
// MODE 0: 128x128 tile, grid 768 1-D; q(*QSCALE)/k scatter into [BH][S][DH];
//         V via LDS transpose into [BH][DH][S] with coalesced 16B stores.
//         XCD swizzle: xcd owns 12n x 8m sub-grid (B 3MB + A 2MB ~ L2-resident).
// MODE 1: 128x64 tile, grid 512 1-D; fp32 out + bias.
//         XCD swizzle: xcd owns 16n x 4m (B 2MB + A 1MB).
template <int MODE>
__global__ __launch_bounds__(256, MODE == 1 ? 4 : 3) void gemm_kernel(
    const u16* __restrict__ A, const u16* __restrict__ Bt,
    const float* __restrict__ bias,
    u16* __restrict__ q_out, u16* __restrict__ k_out, u16* __restrict__ v_out,
    float* __restrict__ out_f32) {
    constexpr int BN = (MODE == 0) ? 128 : 64;
    constexpr int MT = (MODE == 0) ? 4 : 2;
    constexpr int K = 1024;
    // single shared pool: As = Smem[0..8192), Bs = Smem[8192..8192+BN*64)
    __shared__ __align__(16) u16 Smem[128 * 64 + BN * 64];
    u16* As = Smem;
    u16* Bs = Smem + 128 * 64;
    int tid = threadIdx.x;
    int lane = tid & 63;
    int w = tid >> 6;
    int n16 = lane & 15, quad = lane >> 4;
    int lrow = lane >> 3, lchunk = lane & 7;

    // XCD-aware block swizzle
    int bi = blockIdx.x;
    int xcd = bi & 7, jb = bi >> 3;
    int n_blk, m_blk;
    if (MODE == 0) {
        n_blk = (xcd & 1) * 12 + (jb % 12);
        m_blk = (xcd >> 1) * 8 + (jb / 12);
    } else {
        n_blk = jb & 15;
        m_blk = xcd * 4 + (jb >> 4);
    }
    int m0 = m_blk * 128, n0 = n_blk * BN;
    int wm_off = (MODE == 0) ? (w >> 1) * 64 : w * 32;
    int wn_off = (MODE == 0) ? (w & 1) * 64 : 0;

    v4f acc[MT][4];
#pragma unroll
    for (int i = 0; i < MT; ++i)
#pragma unroll
        for (int j = 0; j < 4; ++j) acc[i][j] = v4f{0, 0, 0, 0};

    for (int k0 = 0; k0 < K; k0 += 64) {
#pragma unroll
        for (int i = 0; i < 4; ++i) {
            int r = w * 32 + i * 8 + lrow;
            int gc = lchunk ^ (r & 7);
            gl_lds(A + (size_t)(m0 + r) * K + k0 + gc * 8, As + (w * 32 + i * 8) * 64);
        }
        if (MODE == 0) {
#pragma unroll
            for (int i = 0; i < 4; ++i) {
                int r = w * 32 + i * 8 + lrow;
                int gc = lchunk ^ (r & 7);
                gl_lds(Bt + (size_t)(n0 + r) * K + k0 + gc * 8, Bs + (w * 32 + i * 8) * 64);
            }
        } else {
#pragma unroll
            for (int i = 0; i < 2; ++i) {
                int r = w * 16 + i * 8 + lrow;
                int gc = lchunk ^ (r & 7);
                gl_lds(Bt + (size_t)(n0 + r) * K + k0 + gc * 8, Bs + (w * 16 + i * 8) * 64);
            }
        }
        __syncthreads();
#pragma unroll
        for (int kk = 0; kk < 64; kk += 32) {
            v8s af[MT], bf[4];
#pragma unroll
            for (int mt = 0; mt < MT; ++mt) {
                int ra = wm_off + mt * 16 + n16;
                af[mt] = *(const v8s*)(As + ra * 64 + ((((kk >> 3) + quad) ^ (ra & 7)) << 3));
            }
#pragma unroll
            for (int nt = 0; nt < 4; ++nt) {
                int rb = wn_off + nt * 16 + n16;
                bf[nt] = *(const v8s*)(Bs + rb * 64 + ((((kk >> 3) + quad) ^ (rb & 7)) << 3));
            }
#pragma unroll
            for (int mt = 0; mt < MT; ++mt)
#pragma unroll
                for (int nt = 0; nt < 4; ++nt)
                    acc[mt][nt] = mfma16(af[mt], bf[nt], acc[mt][nt]);
        }
        __syncthreads();
    }

    if (MODE == 1) {
#pragma unroll
        for (int mt = 0; mt < MT; ++mt)
#pragma unroll
            for (int nt = 0; nt < 4; ++nt)
#pragma unroll
                for (int r = 0; r < 4; ++r) {
                    int row = m0 + wm_off + mt * 16 + quad * 4 + r;
                    int col = n0 + nt * 16 + n16;
                    out_f32[(size_t)row * 1024 + col] = acc[mt][nt][r] + bias[col];
                }
        return;
    }

    // ---- MODE 0 epilogue ----
    int which = n0 >> 10;  // whole block is q (0), k (1) or v (2)
    if (which < 2) {
        u16* dst = which ? k_out : q_out;
        float sc = which ? 1.0f : QSCALE;
#pragma unroll
        for (int mt = 0; mt < 4; ++mt)
#pragma unroll
            for (int nt = 0; nt < 4; ++nt) {
                int colb = n0 + wn_off + nt * 16;
                int rowb = m0 + wm_off + mt * 16 + quad * 4;
                int hb = (colb & 1023) >> 6;
                int d = (colb & 63) + n16;
                int b = rowb >> 11, s = rowb & 2047;
                int bh = b * 16 + hb;
#pragma unroll
                for (int r = 0; r < 4; ++r)
                    dst[((size_t)bh * S_LEN + s + r) * DH + d] = f2bf(acc[mt][nt][r] * sc);
            }
    } else {
        // V: transpose 128s x 128d tile through LDS, write V^T[bh][d][s] with
        // 16B/lane stores (lane pairs give 256B contiguous runs per d-row).
        // Two passes over d-halves (head h = 2*(n_blk-16)+p); T = 64 d x 136 s u16.
        int b = m0 >> 11, s0 = m0 & 2047;
        u16* T = Smem;  // 64*136 u16 = 17408 B <= 32 KB pool
#pragma unroll
        for (int p = 0; p < 2; ++p) {
            __syncthreads();
            if ((w & 1) == p) {
#pragma unroll
                for (int mt = 0; mt < 4; ++mt)
#pragma unroll
                    for (int nt = 0; nt < 4; ++nt) {
                        int d = nt * 16 + n16;
                        int sl = (w >> 1) * 64 + mt * 16 + quad * 4;
                        u16x4v pk;
#pragma unroll
                        for (int r = 0; r < 4; ++r) pk[r] = f2bf(acc[mt][nt][r]);
                        *(u16x4v*)(T + d * 136 + sl) = pk;
                    }
            }
            __syncthreads();
            int h = 2 * (n_blk - 16) + p;
            int bh = b * 16 + h;
            int d = tid >> 2;          // 0..63
            int part = tid & 3;        // 64B sub-run
            u16* gp = v_out + ((size_t)bh * DH + d) * S_LEN + s0 + part * 32;
            const u16* tp = T + d * 136 + part * 32;
#pragma unroll
            for (int i = 0; i < 4; ++i)
                *(u16x8v*)(gp + i * 8) = *(const u16x8v*)(tp + i * 8);
        }
    }
}

// ---------------- flash attention (causal), S^T variant, V direct-from-global ---
// Scores computed transposed (mfma(K,Q)): lane holds q=n16, keys quad*4+r per tile.
// K staged in LDS (double-buffered, shared by 4 waves). V^T fragments read
// DIRECTLY from global into VGPRs (L2-resident; every wave needs the full V
// tile anyway, so LDS staging saved nothing) — issued at iteration top,
// consumed at PV, latency pipelined outside the barrier dependence.
// P packed as bf16 pairs -> 4 ds_write_b64/iter (wave-private Ps, no barrier),
// read back as A-frag (b128) with 16B-chunk XOR swizzle.
// Fixed m=0 softmax (scores bounded), per-lane partial l.
template <bool DIAG>
__device__ __forceinline__ void attn_step(const u16* __restrict__ ks,
                                          const u16* __restrict__ vt,  // Vt + kb
                                          u16* __restrict__ pw,
                                          v8s qa0, v8s qa1,
                                          v4f* acc, float& l,
                                          int n16, int quad, int wq) {
    // hoisted V fragment loads (global; independent of K staging/barrier)
    v8s vlo[4];
#pragma unroll
    for (int f = 0; f < 4; ++f) {
        const u16* vr = vt + (size_t)(f * 16 + n16) * S_LEN;
        vlo[f] = *(const v8s*)(vr + quad * 8);
    }

    // S^T tiles: st[nt] = K_tile(nt) . Q^T -> D[key][q]
    v4f st[4];
#pragma unroll
    for (int nt = 0; nt < 4; ++nt) {
        int rk = nt * 16 + n16;
        const u16* kr = ks + rk * 64;
        v4f t = v4f{0, 0, 0, 0};
        t = mfma16(*(const v8s*)(kr + ((quad ^ (rk & 7)) << 3)), qa0, t);
        t = mfma16(*(const v8s*)(kr + (((4 + quad) ^ (rk & 7)) << 3)), qa1, t);
        st[nt] = t;
    }

    v8s vhi[4];
#pragma unroll
    for (int f = 0; f < 4; ++f) {
        const u16* vr = vt + (size_t)(f * 16 + n16) * S_LEN;
        vhi[f] = *(const v8s*)(vr + 32 + quad * 8);
    }

    int h = n16 & 7;
    u16* prow = pw + n16 * 64;
#pragma unroll
    for (int nt = 0; nt < 4; ++nt) {
        float e[4];
#pragma unroll
        for (int r = 0; r < 4; ++r) {
            float v = EXP2(st[nt][r]);
            if (DIAG) {
                if (nt * 16 + quad * 4 + r > wq) v = 0.0f;
            }
            e[r] = v;
            l += v;
        }
        u32x2 pk;
        pk[0] = pack2bf(e[0], e[1]);
        pk[1] = pack2bf(e[2], e[3]);
        *(u32x2*)(prow + (((2 * nt + (quad >> 1)) ^ h) << 3) + (quad & 1) * 4) = pk;
    }
    v8s pa0 = *(const v8s*)(prow + ((quad ^ h) << 3));
    v8s pa1 = *(const v8s*)(prow + (((4 + quad) ^ h) << 3));
#pragma unroll
    for (int f = 0; f < 4; ++f) acc[f] = mfma16(pa0, vlo[f], acc[f]);
#pragma unroll
    for (int f = 0; f < 4; ++f) acc[f] = mfma16(pa1, vhi[f], acc[f]);
}

// grid: 1024 blocks = one (bh, qt) each. XCD-aware: xcd = blk&7 handles bh in
// [xcd*4, xcd*4+4). Balanced qt schedule: with blocks->CU round-robin, CU g's
// four blocks get qts {31-g, 16+g, 15-g, g} whose (qt+1) sums are 66 for every
// g — static balance; heaviest tiles dispatch first. LDS 24576 B (Ks dbuf + Ps)
// -> capacity >= 5 blocks/CU, all 4 dispatched blocks resident.
__global__ __launch_bounds__(256, 5) void attn_kernel(const u16* __restrict__ Qg,
                                                      const u16* __restrict__ Kg,
                                                      const u16* __restrict__ Vtg,
                                                      u16* __restrict__ ctx) {
    __shared__ __align__(16) u16 Ks[2][64 * 64];
    __shared__ __align__(16) u16 Ps[4][16 * 64];

    int i = blockIdx.x;
    int xcd = i & 7;
    int j = i >> 3;               // 0..127
    int bh = xcd * 4 + (j & 3);   // 0..31
    int idx = j >> 2;             // 0..31
    int i0 = idx & 7, m = idx >> 3;
    int qt = (m == 0) ? (31 - i0) : (m == 1) ? (16 + i0) : (m == 2) ? (15 - i0) : i0;
    int qbase = qt * 64;
    int tid = threadIdx.x;
    int w = tid >> 6;
    int lane = tid & 63;
    int n16 = lane & 15;
    int quad = lane >> 4;
    int lrow = lane >> 3, lchunk = lane & 7;

    const u16* Qb = Qg + (size_t)bh * (S_LEN * DH);
    const u16* Kb = Kg + (size_t)bh * (S_LEN * DH);
    const u16* Vtb = Vtg + (size_t)bh * (S_LEN * DH);
    u16* pw = Ps[w];
    int b = bh >> 4, h = bh & 15;
    int cur = 0;

    auto stage = [&](int kb, int buf) {
#pragma unroll
        for (int i2 = 0; i2 < 2; ++i2) {
            int r = w * 16 + i2 * 8 + lrow;
            int gc = lchunk ^ (r & 7);
            gl_lds(Kb + (size_t)(kb + r) * DH + gc * 8, &Ks[buf][(w * 16 + i2 * 8) * 64]);
        }
    };

    int qrow = qbase + w * 16 + n16;
    v8s qa0 = *(const v8s*)(Qb + (size_t)qrow * DH + quad * 8);
    v8s qa1 = *(const v8s*)(Qb + (size_t)qrow * DH + 32 + quad * 8);

    v4f acc[4];
#pragma unroll
    for (int f = 0; f < 4; ++f) acc[f] = v4f{0, 0, 0, 0};
    float l = 0.0f;
    int wq = w * 16 + n16;   // query index relative to qbase (lane's query)
    int nkb = qt + 1;

    stage(0, cur);
    for (int it = 0; it < nkb - 1; ++it) {
        __syncthreads();
        stage((it + 1) * 64, cur ^ 1);
        attn_step<false>(Ks[cur], Vtb + it * 64, pw, qa0, qa1, acc, l, n16, quad, wq);
        cur ^= 1;
    }
    __syncthreads();
    attn_step<true>(Ks[cur], Vtb + (nkb - 1) * 64, pw, qa0, qa1, acc, l, n16, quad, wq);

    // epilogue: l reduce across quads (lanes n16, n16+16, +32, +48 hold q=n16)
    l += __shfl_xor(l, 16);
    l += __shfl_xor(l, 32);
    // acc rows are q = quad*4 + r: fetch matching l via shfl from lane quad*4+r
#pragma unroll
    for (int r = 0; r < 4; ++r) {
        float lq = __shfl(l, quad * 4 + r);
        float inv = 1.0f / lq;
        int srow = qbase + w * 16 + quad * 4 + r;
        size_t base = ((size_t)(b * S_LEN + srow)) * D_MODEL + h * DH;
#pragma unroll
        for (int f = 0; f < 4; ++f)
            ctx[base + f * 16 + n16] = f2bf(acc[f][r] * inv);
    }
}

extern "C" void kernel_launch(void* const* d_in, const int* in_sizes, int n_in,
                              void* d_out, int out_size, void* d_ws, size_t ws_size,
                              hipStream_t stream) {
    const float* x  = (const float*)d_in[0];
    const float* Wq = (const float*)d_in[1];
    const float* Wk = (const float*)d_in[2];
    const float* Wv = (const float*)d_in[3];
    const float* Wo = (const float*)d_in[4];
    const float* bo = (const float*)d_in[5];
    float* out = (float*)d_out;

    char* ws = (char*)d_ws;
    u16* x_bf = (u16*)ws;   ws += (size_t)BS_ROWS * D_MODEL * 2;
    u16* wqkv = (u16*)ws;   ws += (size_t)3 * D_MODEL * D_MODEL * 2;
    u16* wo_t = (u16*)ws;   ws += (size_t)D_MODEL * D_MODEL * 2;
    u16* qbuf = (u16*)ws;   ws += (size_t)BS_ROWS * D_MODEL * 2;
    u16* kbuf = (u16*)ws;   ws += (size_t)BS_ROWS * D_MODEL * 2;
    u16* vtbuf = (u16*)ws;  ws += (size_t)BS_ROWS * D_MODEL * 2;
    u16* ctx = (u16*)ws;    ws += (size_t)BS_ROWS * D_MODEL * 2;

    prep_kernel<<<5120, 256, 0, stream>>>(x, Wq, Wk, Wv, Wo, x_bf, wqkv, wo_t);

    gemm_kernel<0><<<768, 256, 0, stream>>>(x_bf, wqkv, nullptr,
                                            qbuf, kbuf, vtbuf, nullptr);
    attn_kernel<<<1024, 256, 0, stream>>>(qbuf, kbuf, vtbuf, ctx);
    gemm_kernel<1><<<512, 256, 0, stream>>>(ctx, wo_t, bo,
                                            nullptr, nullptr, nullptr, out);
}

// Round 11
// 165.091 us; speedup vs baseline: 1.2677x; 1.2677x over previous
//
#include <hip/hip_runtime.h>
#include <math.h>

typedef unsigned short u16;
typedef unsigned int u32;
typedef short v8s __attribute__((ext_vector_type(8)));
typedef float v4f __attribute__((ext_vector_type(4)));
typedef u16 u16x4v __attribute__((ext_vector_type(4)));
typedef u16 u16x8v __attribute__((ext_vector_type(8)));
typedef u32 u32x2 __attribute__((ext_vector_type(2)));

#define S_LEN 2048
#define D_MODEL 1024
#define DH 64
#define BS_ROWS 4096  // B*S

// Q prescale: 1/sqrt(64) * log2(e), so softmax exp(x/8) == 2^(q_scaled . k)
#define QSCALE 0.1803368801111204f

#if __has_builtin(__builtin_amdgcn_exp2f)
#define EXP2(x) __builtin_amdgcn_exp2f(x)
#else
#define EXP2(x) __expf(0.6931471805599453f * (x))
#endif

__device__ __forceinline__ u16 f2bf(float f) {
    union { float f; unsigned int u; } c; c.f = f;
    unsigned int u = c.u;
    unsigned int r = (u + 0x7FFFu + ((u >> 16) & 1u)) >> 16;
    return (u16)r;
}
// pack two positive finite floats to bf16 pair (round-to-nearest, no tie-even)
__device__ __forceinline__ u32 pack2bf(float a, float b) {
    u32 ua = __float_as_uint(a) + 0x8000u;
    u32 ub = __float_as_uint(b) + 0x8000u;
    return (ua >> 16) | (ub & 0xFFFF0000u);
}

__device__ __forceinline__ v4f mfma16(v8s a, v8s b, v4f c) {
    return __builtin_amdgcn_mfma_f32_16x16x32_bf16(a, b, c, 0, 0, 0);
}

// async global->LDS, 16B per lane; LDS dest = base + lane*16 (wave-uniform base)
__device__ __forceinline__ void gl_lds(const u16* g, u16* l) {
    __builtin_amdgcn_global_load_lds(
        (const __attribute__((address_space(1))) void*)g,
        (__attribute__((address_space(3))) void*)l, 16, 0, 0);
}

// ---------------- prep: cast x (blocks 0..2047, 32B/thread) + pack W^T ----------
__global__ __launch_bounds__(256) void prep_kernel(const float* __restrict__ x,
                                                   const float* __restrict__ Wq,
                                                   const float* __restrict__ Wk,
                                                   const float* __restrict__ Wv,
                                                   const float* __restrict__ Wo,
                                                   u16* __restrict__ xb,
                                                   u16* __restrict__ wqkv,
                                                   u16* __restrict__ wo_t) {
    __shared__ u16 tile[64][72];
    int blk = blockIdx.x;
    int t = threadIdx.x;
    if (blk < 2048) {
        size_t base = ((size_t)blk * 256 + t) * 8;   // 8 floats per thread
        float4 v0 = *(const float4*)(x + base);
        float4 v1 = *(const float4*)(x + base + 4);
        u16x8v o;
        o[0] = f2bf(v0.x); o[1] = f2bf(v0.y); o[2] = f2bf(v0.z); o[3] = f2bf(v0.w);
        o[4] = f2bf(v1.x); o[5] = f2bf(v1.y); o[6] = f2bf(v1.z); o[7] = f2bf(v1.w);
        *(u16x8v*)(xb + base) = o;
        return;
    }
    int pb = blk - 2048;
    int z = pb >> 8;  // 0..3
    pb &= 255;
    const float* w = (z == 0) ? Wq : (z == 1) ? Wk : (z == 2) ? Wv : Wo;
    u16* wt = (z < 3) ? (wqkv + (size_t)z * 1024 * 1024) : wo_t;
    int k0 = (pb & 15) * 64, n0 = (pb >> 4) * 64;
    int tr = t >> 4;          // 0..15
    int tc = (t & 15) * 4;    // 0..60
#pragma unroll
    for (int i = 0; i < 4; ++i) {
        int k = tr + 16 * i;
        float4 v = *(const float4*)(w + (size_t)(k0 + k) * 1024 + n0 + tc);
        tile[tc + 0][k] = f2bf(v.x);
        tile[tc + 1][k] = f2bf(v.y);
        tile[tc + 2][k] = f2bf(v.z);
        tile[tc + 3][k] = f2bf(v.w);
    }
    __syncthreads();
#pragma unroll
    for (int i = 0; i < 4; ++i) {
        int n = tr + 16 * i;
        u16x4v o;
        o[0] = tile[n][tc]; o[1] = tile[n][tc + 1];
        o[2] = tile[n][tc + 2]; o[3] = tile[n][tc + 3];
        *(u16x4v*)(wt + (size_t)(n0 + n) * 1024 + k0 + tc) = o;
    }
}

// ---------------- GEMM: C[M,N] = A[M,K] x Bt[N,K] ----------------
// MODE 0: 128x128 tile, grid 768 1-D; q(*QSCALE)/k scatter into [BH][S][DH];
//         V via LDS transpose into [BH][DH][S] with coalesced 16B stores.
//         XCD swizzle: xcd owns 12n x 8m sub-grid (B 3MB + A 2MB ~ L2-resident).
// MODE 1: 128x64 tile, grid 512 1-D; fp32 out + bias.
//         XCD swizzle: xcd owns 16n x 4m (B 2MB + A 1MB).
template <int MODE>
__global__ __launch_bounds__(256, MODE == 1 ? 4 : 3) void gemm_kernel(
    const u16* __restrict__ A, const u16* __restrict__ Bt,
    const float* __restrict__ bias,
    u16* __restrict__ q_out, u16* __restrict__ k_out, u16* __restrict__ v_out,
    float* __restrict__ out_f32) {
    constexpr int BN = (MODE == 0) ? 128 : 64;
    constexpr int MT = (MODE == 0) ? 4 : 2;
    constexpr int K = 1024;
    // single shared pool: As = Smem[0..8192), Bs = Smem[8192..8192+BN*64)
    __shared__ __align__(16) u16 Smem[128 * 64 + BN * 64];
    u16* As = Smem;
    u16* Bs = Smem + 128 * 64;
    int tid = threadIdx.x;
    int lane = tid & 63;
    int w = tid >> 6;
    int n16 = lane & 15, quad = lane >> 4;
    int lrow = lane >> 3, lchunk = lane & 7;

    // XCD-aware block swizzle
    int bi = blockIdx.x;
    int xcd = bi & 7, jb = bi >> 3;
    int n_blk, m_blk;
    if (MODE == 0) {
        n_blk = (xcd & 1) * 12 + (jb % 12);
        m_blk = (xcd >> 1) * 8 + (jb / 12);
    } else {
        n_blk = jb & 15;
        m_blk = xcd * 4 + (jb >> 4);
    }
    int m0 = m_blk * 128, n0 = n_blk * BN;
    int wm_off = (MODE == 0) ? (w >> 1) * 64 : w * 32;
    int wn_off = (MODE == 0) ? (w & 1) * 64 : 0;

    v4f acc[MT][4];
#pragma unroll
    for (int i = 0; i < MT; ++i)
#pragma unroll
        for (int j = 0; j < 4; ++j) acc[i][j] = v4f{0, 0, 0, 0};

    for (int k0 = 0; k0 < K; k0 += 64) {
#pragma unroll
        for (int i = 0; i < 4; ++i) {
            int r = w * 32 + i * 8 + lrow;
            int gc = lchunk ^ (r & 7);
            gl_lds(A + (size_t)(m0 + r) * K + k0 + gc * 8, As + (w * 32 + i * 8) * 64);
        }
        if (MODE == 0) {
#pragma unroll
            for (int i = 0; i < 4; ++i) {
                int r = w * 32 + i * 8 + lrow;
                int gc = lchunk ^ (r & 7);
                gl_lds(Bt + (size_t)(n0 + r) * K + k0 + gc * 8, Bs + (w * 32 + i * 8) * 64);
            }
        } else {
#pragma unroll
            for (int i = 0; i < 2; ++i) {
                int r = w * 16 + i * 8 + lrow;
                int gc = lchunk ^ (r & 7);
                gl_lds(Bt + (size_t)(n0 + r) * K + k0 + gc * 8, Bs + (w * 16 + i * 8) * 64);
            }
        }
        __syncthreads();
#pragma unroll
        for (int kk = 0; kk < 64; kk += 32) {
            v8s af[MT], bf[4];
#pragma unroll
            for (int mt = 0; mt < MT; ++mt) {
                int ra = wm_off + mt * 16 + n16;
                af[mt] = *(const v8s*)(As + ra * 64 + ((((kk >> 3) + quad) ^ (ra & 7)) << 3));
            }
#pragma unroll
            for (int nt = 0; nt < 4; ++nt) {
                int rb = wn_off + nt * 16 + n16;
                bf[nt] = *(const v8s*)(Bs + rb * 64 + ((((kk >> 3) + quad) ^ (rb & 7)) << 3));
            }
#pragma unroll
            for (int mt = 0; mt < MT; ++mt)
#pragma unroll
                for (int nt = 0; nt < 4; ++nt)
                    acc[mt][nt] = mfma16(af[mt], bf[nt], acc[mt][nt]);
        }
        __syncthreads();
    }

    if (MODE == 1) {
#pragma unroll
        for (int mt = 0; mt < MT; ++mt)
#pragma unroll
            for (int nt = 0; nt < 4; ++nt)
#pragma unroll
                for (int r = 0; r < 4; ++r) {
                    int row = m0 + wm_off + mt * 16 + quad * 4 + r;
                    int col = n0 + nt * 16 + n16;
                    out_f32[(size_t)row * 1024 + col] = acc[mt][nt][r] + bias[col];
                }
        return;
    }

    // ---- MODE 0 epilogue ----
    int which = n0 >> 10;  // whole block is q (0), k (1) or v (2)
    if (which < 2) {
        u16* dst = which ? k_out : q_out;
        float sc = which ? 1.0f : QSCALE;
#pragma unroll
        for (int mt = 0; mt < 4; ++mt)
#pragma unroll
            for (int nt = 0; nt < 4; ++nt) {
                int colb = n0 + wn_off + nt * 16;
                int rowb = m0 + wm_off + mt * 16 + quad * 4;
                int hb = (colb & 1023) >> 6;
                int d = (colb & 63) + n16;
                int b = rowb >> 11, s = rowb & 2047;
                int bh = b * 16 + hb;
#pragma unroll
                for (int r = 0; r < 4; ++r)
                    dst[((size_t)bh * S_LEN + s + r) * DH + d] = f2bf(acc[mt][nt][r] * sc);
            }
    } else {
        // V: transpose 128s x 128d tile through LDS, write V^T[bh][d][s] with
        // 16B/lane stores (lane pairs give 256B contiguous runs per d-row).
        // Two passes over d-halves (head h = 2*(n_blk-16)+p); T = 64 d x 136 s u16.
        int b = m0 >> 11, s0 = m0 & 2047;
        u16* T = Smem;  // 64*136 u16 = 17408 B <= 32 KB pool
#pragma unroll
        for (int p = 0; p < 2; ++p) {
            __syncthreads();
            if ((w & 1) == p) {
#pragma unroll
                for (int mt = 0; mt < 4; ++mt)
#pragma unroll
                    for (int nt = 0; nt < 4; ++nt) {
                        int d = nt * 16 + n16;
                        int sl = (w >> 1) * 64 + mt * 16 + quad * 4;
                        u16x4v pk;
#pragma unroll
                        for (int r = 0; r < 4; ++r) pk[r] = f2bf(acc[mt][nt][r]);
                        *(u16x4v*)(T + d * 136 + sl) = pk;
                    }
            }
            __syncthreads();
            int h = 2 * (n_blk - 16) + p;
            int bh = b * 16 + h;
            int d = tid >> 2;          // 0..63
            int part = tid & 3;        // 64B sub-run
            u16* gp = v_out + ((size_t)bh * DH + d) * S_LEN + s0 + part * 32;
            const u16* tp = T + d * 136 + part * 32;
#pragma unroll
            for (int i = 0; i < 4; ++i)
                *(u16x8v*)(gp + i * 8) = *(const u16x8v*)(tp + i * 8);
        }
    }
}

// ---------------- flash attention (causal), S^T variant ----------------
// Scores computed transposed (mfma(K,Q)): lane holds q=n16, keys quad*4+r per tile.
// P packed as bf16 pairs -> 4 ds_write_b64/iter, read back as A-frag (b128) with
// 16B-chunk XOR swizzle. Fixed m=0 softmax (scores bounded), per-lane partial l.
// K,V staged via global_load_lds, double-buffered; V kept in LDS (shared by all
// 4 waves — direct-global V was a 2x regression, round-10 lesson).
template <bool DIAG>
__device__ __forceinline__ void attn_step(const u16* __restrict__ ks,
                                          const u16* __restrict__ vs,
                                          u16* __restrict__ pw,
                                          v8s qa0, v8s qa1,
                                          v4f* acc, float& l,
                                          int n16, int quad, int wq) {
    // S^T tiles: st[nt] = K_tile(nt) . Q^T -> D[key][q]
    v4f st[4];
#pragma unroll
    for (int nt = 0; nt < 4; ++nt) {
        int rk = nt * 16 + n16;
        const u16* kr = ks + rk * 64;
        v4f t = v4f{0, 0, 0, 0};
        t = mfma16(*(const v8s*)(kr + ((quad ^ (rk & 7)) << 3)), qa0, t);
        t = mfma16(*(const v8s*)(kr + (((4 + quad) ^ (rk & 7)) << 3)), qa1, t);
        st[nt] = t;
    }
    int h = n16 & 7;
    u16* prow = pw + n16 * 64;
#pragma unroll
    for (int nt = 0; nt < 4; ++nt) {
        float e[4];
#pragma unroll
        for (int r = 0; r < 4; ++r) {
            float v = EXP2(st[nt][r]);
            if (DIAG) {
                if (nt * 16 + quad * 4 + r > wq) v = 0.0f;
            }
            e[r] = v;
            l += v;
        }
        u32x2 pk;
        pk[0] = pack2bf(e[0], e[1]);
        pk[1] = pack2bf(e[2], e[3]);
        *(u32x2*)(prow + (((2 * nt + (quad >> 1)) ^ h) << 3) + (quad & 1) * 4) = pk;
    }
    v8s pa0 = *(const v8s*)(prow + ((quad ^ h) << 3));
    v8s pa1 = *(const v8s*)(prow + (((4 + quad) ^ h) << 3));
#pragma unroll
    for (int f = 0; f < 4; ++f) {
        int rv = f * 16 + n16;
        const u16* vr = vs + rv * 64;
        acc[f] = mfma16(pa0, *(const v8s*)(vr + ((quad ^ (rv & 7)) << 3)), acc[f]);
        acc[f] = mfma16(pa1, *(const v8s*)(vr + (((4 + quad) ^ (rv & 7)) << 3)), acc[f]);
    }
}

// grid: 1024 blocks = one (bh, qt) each. XCD-aware: xcd = blk&7 handles bh in
// [xcd*4, xcd*4+4). Balanced qt schedule: under per-XCD round-robin CU
// placement, CU g's four blocks get qts {31-g, 16+g, 15-g, g} (sum 66 each).
// LDS 40960 B -> 4 blocks/CU (latency-bound: maximize resident waves).
__global__ __launch_bounds__(256, 4) void attn_kernel(const u16* __restrict__ Qg,
                                                      const u16* __restrict__ Kg,
                                                      const u16* __restrict__ Vtg,
                                                      u16* __restrict__ ctx) {
    __shared__ __align__(16) u16 Ks[2][64 * 64];
    __shared__ __align__(16) u16 Vs[2][64 * 64];
    __shared__ __align__(16) u16 Ps[4][16 * 64];

    int i = blockIdx.x;
    int xcd = i & 7;
    int j = i >> 3;               // 0..127
    int bh = xcd * 4 + (j & 3);   // 0..31
    int idx = j >> 2;             // 0..31
    int i0 = idx & 7, m = idx >> 3;
    int qt = (m == 0) ? (31 - i0) : (m == 1) ? (16 + i0) : (m == 2) ? (15 - i0) : i0;
    int qbase = qt * 64;
    int tid = threadIdx.x;
    int w = tid >> 6;
    int lane = tid & 63;
    int n16 = lane & 15;
    int quad = lane >> 4;
    int lrow = lane >> 3, lchunk = lane & 7;

    const u16* Qb = Qg + (size_t)bh * (S_LEN * DH);
    const u16* Kb = Kg + (size_t)bh * (S_LEN * DH);
    const u16* Vtb = Vtg + (size_t)bh * (S_LEN * DH);
    u16* pw = Ps[w];
    int b = bh >> 4, h = bh & 15;
    int cur = 0;

    auto stage = [&](int kb, int buf) {
#pragma unroll
        for (int i2 = 0; i2 < 2; ++i2) {
            int r = w * 16 + i2 * 8 + lrow;
            int gc = lchunk ^ (r & 7);
            gl_lds(Kb + (size_t)(kb + r) * DH + gc * 8, &Ks[buf][(w * 16 + i2 * 8) * 64]);
            gl_lds(Vtb + (size_t)r * S_LEN + kb + gc * 8, &Vs[buf][(w * 16 + i2 * 8) * 64]);
        }
    };

    int qrow = qbase + w * 16 + n16;
    v8s qa0 = *(const v8s*)(Qb + (size_t)qrow * DH + quad * 8);
    v8s qa1 = *(const v8s*)(Qb + (size_t)qrow * DH + 32 + quad * 8);

    v4f acc[4];
#pragma unroll
    for (int f = 0; f < 4; ++f) acc[f] = v4f{0, 0, 0, 0};
    float l = 0.0f;
    int wq = w * 16 + n16;   // query index relative to qbase (lane's query)
    int nkb = qt + 1;

    stage(0, cur);
    for (int it = 0; it < nkb - 1; ++it) {
        __syncthreads();
        stage((it + 1) * 64, cur ^ 1);
        attn_step<false>(Ks[cur], Vs[cur], pw, qa0, qa1, acc, l, n16, quad, wq);
        cur ^= 1;
    }
    __syncthreads();
    attn_step<true>(Ks[cur], Vs[cur], pw, qa0, qa1, acc, l, n16, quad, wq);

    // epilogue: l reduce across quads (lanes n16, n16+16, +32, +48 hold q=n16)
    l += __shfl_xor(l, 16);
    l += __shfl_xor(l, 32);
    // acc rows are q = quad*4 + r: fetch matching l via shfl from lane quad*4+r
#pragma unroll
    for (int r = 0; r < 4; ++r) {
        float lq = __shfl(l, quad * 4 + r);
        float inv = 1.0f / lq;
        int srow = qbase + w * 16 + quad * 4 + r;
        size_t base = ((size_t)(b * S_LEN + srow)) * D_MODEL + h * DH;
#pragma unroll
        for (int f = 0; f < 4; ++f)
            ctx[base + f * 16 + n16] = f2bf(acc[f][r] * inv);
    }
}

extern "C" void kernel_launch(void* const* d_in, const int* in_sizes, int n_in,
                              void* d_out, int out_size, void* d_ws, size_t ws_size,
                              hipStream_t stream) {
    const float* x  = (const float*)d_in[0];
    const float* Wq = (const float*)d_in[1];
    const float* Wk = (const float*)d_in[2];
    const float* Wv = (const float*)d_in[3];
    const float* Wo = (const float*)d_in[4];
    const float* bo = (const float*)d_in[5];
    float* out = (float*)d_out;

    char* ws = (char*)d_ws;
    u16* x_bf = (u16*)ws;   ws += (size_t)BS_ROWS * D_MODEL * 2;
    u16* wqkv = (u16*)ws;   ws += (size_t)3 * D_MODEL * D_MODEL * 2;
    u16* wo_t = (u16*)ws;   ws += (size_t)D_MODEL * D_MODEL * 2;
    u16* qbuf = (u16*)ws;   ws += (size_t)BS_ROWS * D_MODEL * 2;
    u16* kbuf = (u16*)ws;   ws += (size_t)BS_ROWS * D_MODEL * 2;
    u16* vtbuf = (u16*)ws;  ws += (size_t)BS_ROWS * D_MODEL * 2;
    u16* ctx = (u16*)ws;    ws += (size_t)BS_ROWS * D_MODEL * 2;

    prep_kernel<<<3072, 256, 0, stream>>>(x, Wq, Wk, Wv, Wo, x_bf, wqkv, wo_t);

    gemm_kernel<0><<<768, 256, 0, stream>>>(x_bf, wqkv, nullptr,
                                            qbuf, kbuf, vtbuf, nullptr);
    attn_kernel<<<1024, 256, 0, stream>>>(qbuf, kbuf, vtbuf, ctx);
    gemm_kernel<1><<<512, 256, 0, stream>>>(ctx, wo_t, bo,
                                            nullptr, nullptr, nullptr, out);
}